// Round 6
// baseline (206.371 us; speedup 1.0000x reference)
//
#include <hip/hip_runtime.h>
#include <cfloat>
#include <climits>

// Problem constants: x (16,2048,256) fp32 -> N=32768 rows; weight (4096,256) fp32.
constexpr int E  = 256;    // quantizing_dim
constexpr int Qn = 4096;   // num_quantizing
constexpr float WSCALE = 4096.0f;   // 2^12 exact pow2 (keeps f16 products well-scaled)

// Round 17: barrier-free K-loop. Five variants (128^2/256^2 tiles, 16-phase,
// counted-vmcnt, fat-acc) all pinned at MfmaUtil 25-32% -- the invariant was
// the per-K-step collective drain, fatal when K is only 4 steps. Key insight:
// the W-tile (256x256x2B = 128KB) fits in LDS WHOLE. So: stage all of W once
// (one __syncthreads, the only collective sync in the kernel); X fragments
// are loaded per-lane directly from global (contiguous 16B, L1-resident
// per-kt working set) and never touch LDS. The K-loop has ZERO barriers and
// ZERO vmcnt drains; W-LDS is read-only after the prologue (race-free by
// construction); 2 waves/SIMD hide LDS + VMEM latency. Accumulation order,
// W staging layout/swizzle, epilogue, finalize: byte-identical to round 12
// (92.2 us validated) -> absmax 0 carries over.

typedef _Float16 half8  __attribute__((ext_vector_type(8)));
typedef _Float16 half4v __attribute__((ext_vector_type(4)));
typedef float    f32x16 __attribute__((ext_vector_type(16)));

#define GAS __attribute__((address_space(1)))
#define LAS __attribute__((address_space(3)))

#define NEG_INF __int_as_float(0xFF800000)

__device__ inline bool lexlt(float a, int ai, float b, int bi) {
    return a < b || (a == b && ai < bi);
}

// ---------------------------------------------------------------------------
// Prep: one 64-lane wave per row (x and w). Emits f16 operand; sumsq only for w.
// (unchanged, validated)
// ---------------------------------------------------------------------------
__global__ __launch_bounds__(256) void prep_kernel(
    const float* __restrict__ x, const float* __restrict__ w,
    _Float16* __restrict__ A16, _Float16* __restrict__ B16,
    float* __restrict__ w2, int nxblocks)
{
    int blk  = blockIdx.x;
    int sub  = threadIdx.x >> 6;
    int lane = threadIdx.x & 63;
    bool isX = blk < nxblocks;
    int row  = (isX ? blk : blk - nxblocks) * 4 + sub;

    const float* src = isX ? x : w;
    float4 v = *(const float4*)(src + (size_t)row * E + lane * 4);

    if (!isX) {
        float s = v.x * v.x + v.y * v.y + v.z * v.z + v.w * v.w;   // UNSCALED sumsq
        #pragma unroll
        for (int off = 32; off; off >>= 1) s += __shfl_xor(s, off);
        if (lane == 0) w2[row] = s;
    }

    float sc = isX ? 1.0f : WSCALE;                            // exact pow2
    half4v h = { (_Float16)(v.x * sc), (_Float16)(v.y * sc),
                 (_Float16)(v.z * sc), (_Float16)(v.w * sc) };
    _Float16* dst16 = (isX ? A16 : B16) + (size_t)row * 256;
    *(half4v*)(dst16 + lane * 4) = h;
}

// ---------------------------------------------------------------------------
// Main MFMA kernel: block = 256 codewords x 256 x-rows, 512 threads (8 waves),
// grid (Qn/256, N/256). Per wave acc[4][2] (128 cw x 64 xr) of 32x32x16 f16.
// W: whole 256x256 tile resident in LDS (staged once). X: per-lane direct
// global loads. Barrier-free K-loop.
// ---------------------------------------------------------------------------
__device__ inline void ins4max(float K[4], float k) {
    #pragma unroll
    for (int t = 0; t < 4; ++t) {            // keep K descending
        float mx = fmaxf(K[t], k);
        k = fminf(K[t], k);
        K[t] = mx;
    }
}

union SmemU {
    _Float16 W[4][256 * 64];        // [kt][row][64 f16] = 128 KB, whole K
    float2 mergeS[256 * 2 * 4];     // 16 KB overlay (post-loop, over W[0])
};

__global__ __launch_bounds__(512, 2) void vq_mfma_kernel(
    const _Float16* __restrict__ A16,      // (N, 256)  xh
    const _Float16* __restrict__ B16,      // (Qn, 256) wh_s
    float4* __restrict__ top4)             // (N, 32) packed {k0,k1,k2,k3} desc
{
    __shared__ SmemU sm;

    const int tid  = threadIdx.x;
    const int w    = tid >> 6;           // 0..7
    const int lane = tid & 63;
    const int l31  = lane & 31;
    const int lh   = lane >> 5;          // k-half select
    const int cwg  = blockIdx.x;         // codeword group (256 codewords)
    const int rb   = blockIdx.y;         // x-row band (256 rows)

    const int wm = w & 1;                // codeword half base: wm*128
    const int wn = w >> 1;               // x-row quarter base: wn*64

    f32x16 acc[4][2];
    #pragma unroll
    for (int m = 0; m < 4; ++m)
        #pragma unroll
        for (int n = 0; n < 2; ++n)
            #pragma unroll
            for (int r = 0; r < 16; ++r) acc[m][n][r] = 0.0f;

    const _Float16* Ab16 = A16 + (size_t)rb  * 256 * 256;
    const _Float16* Bb16 = B16 + (size_t)cwg * 256 * 256;

    const int srow = lane >> 3;   // staging: row-in-8 group
    const int schk = lane & 7;    // staging: dest 16B chunk

    // ---- prologue: stage the ENTIRE W tile (all 4 K-slices) into LDS ----
    // LDS stays linear per 8-row group (gload_lds constraint); the chunk
    // swizzle lives in the pre-swizzled GLOBAL source (rule #21 involution).
    // 16 gload_lds per wave; one drain; W-LDS is read-only afterwards.
    #pragma unroll
    for (int kt = 0; kt < 4; ++kt) {
        #pragma unroll
        for (int inst = 0; inst < 4; ++inst) {
            int drow = w * 32 + inst * 8 + srow;          // 0..255
            int gchk = schk ^ (drow & 7);                 // source chunk swizzle
            const _Float16* gW = Bb16 + (size_t)drow * 256 + kt * 64 + gchk * 8;
            __builtin_amdgcn_global_load_lds((const GAS void*)gW,
                (LAS void*)(&sm.W[kt][0] + w * 2048 + inst * 512), 16, 0, 0);
        }
    }
    __syncthreads();               // the ONLY collective drain in this kernel

    // X row base pointers (per-lane, fixed rows for the whole K-loop)
    const _Float16* Xb0 = Ab16 + (size_t)(wn * 64 +  0 + l31) * 256;
    const _Float16* Xb1 = Ab16 + (size_t)(wn * 64 + 32 + l31) * 256;

    // ---- barrier-free K-loop ----
    #pragma unroll
    for (int kt = 0; kt < 4; ++kt) {
        const _Float16* Wb = &sm.W[kt][0];

        #pragma unroll
        for (int s = 0; s < 4; ++s) {
            const int kc = 2 * s + lh;

            // X fragments: direct global loads (contiguous 16B, L1-warm)
            half8 xf[2];
            xf[0] = *(const half8*)(Xb0 + kt * 64 + kc * 8);
            xf[1] = *(const half8*)(Xb1 + kt * 64 + kc * 8);

            // W fragments: LDS reads (same addressing as validated rounds)
            half8 wf[4];
            #pragma unroll
            for (int m = 0; m < 4; ++m) {
                int fr = wm * 128 + m * 32 + l31;
                wf[m] = *(const half8*)(Wb + fr * 64 + ((kc ^ (fr & 7)) << 3));
            }

            __builtin_amdgcn_s_setprio(1);
            #pragma unroll
            for (int m = 0; m < 4; ++m)
                #pragma unroll
                for (int n = 0; n < 2; ++n)
                    acc[m][n] = __builtin_amdgcn_mfma_f32_32x32x16_f16(
                        wf[m], xf[n], acc[m][n], 0, 0, 0);
            __builtin_amdgcn_s_setprio(0);
        }
    }

    // ---- epilogue: packed key = (bits(acc) & ~0xFFF) | qg; maximize ----
    // Retention granularity identical to the validated versions:
    // per lane, top-2 over each {2 m-frags x 16 regs} = 32-codeword group.
    float t1[2][2], t2[2][2];      // [g2][n]
    #pragma unroll
    for (int g2 = 0; g2 < 2; ++g2)
        #pragma unroll
        for (int n = 0; n < 2; ++n) { t1[g2][n] = NEG_INF; t2[g2][n] = NEG_INF; }

    #pragma unroll
    for (int m = 0; m < 4; ++m) {
        const int g2 = m >> 1;
        #pragma unroll
        for (int r = 0; r < 16; ++r) {
            int crow = (r & 3) + 8 * (r >> 2) + 4 * lh;   // C-row mapping (32x32)
            int qg   = cwg * 256 + wm * 128 + m * 32 + crow;  // global codeword id
            #pragma unroll
            for (int n = 0; n < 2; ++n) {
                float pk = __int_as_float(
                    (__float_as_int(acc[m][n][r]) & 0xFFFFF000) | qg);
                t2[g2][n] = __builtin_amdgcn_fmed3f(t1[g2][n], t2[g2][n], pk);
                t1[g2][n] = fmaxf(t1[g2][n], pk);
            }
        }
    }

    __syncthreads();   // all W reads done -> overlay mergeS

    #pragma unroll
    for (int n = 0; n < 2; ++n) {
        int xrow = wn * 64 + n * 32 + l31;
        #pragma unroll
        for (int g2 = 0; g2 < 2; ++g2)
            sm.mergeS[(xrow * 2 + wm) * 4 + (lh * 2 + g2)] =
                make_float2(t1[g2][n], t2[g2][n]);
    }
    __syncthreads();

    {
        int xrow = tid >> 1, cgl = tid & 1;   // 512 threads = 256 rows x 2 cgs
        float K[4] = { NEG_INF, NEG_INF, NEG_INF, NEG_INF };
        #pragma unroll
        for (int sl = 0; sl < 4; ++sl) {
            float2 a = sm.mergeS[(xrow * 2 + cgl) * 4 + sl];
            ins4max(K, a.x);
            ins4max(K, a.y);
        }
        top4[(size_t)(rb * 256 + xrow) * 32 + cwg * 2 + cgl] =
            make_float4(K[0], K[1], K[2], K[3]);
    }
}

// ---------------------------------------------------------------------------
// Finalize: per row, 32 cg x top-4 packed candidates -> global top-4 by packed
// key (wave-max passes w/ bitwise invalidation) -> exact fp32 rescore
// (reference formula + first-index tie-break), write outputs. (unchanged)
// ---------------------------------------------------------------------------
__global__ __launch_bounds__(256) void finalize_kernel(
    const float4* __restrict__ top4, const float* __restrict__ x,
    const float* __restrict__ w, const float* __restrict__ w2,
    float* __restrict__ qdata, float* __restrict__ qidx)
{
    int row  = blockIdx.x * 4 + (threadIdx.x >> 6);
    int lane = threadIdx.x & 63;

    float cand[4];
    if (lane < 32) {
        float4 c4 = top4[(size_t)row * 32 + lane];
        cand[0] = c4.x; cand[1] = c4.y; cand[2] = c4.z; cand[3] = c4.w;
    } else {
        cand[0] = cand[1] = cand[2] = cand[3] = NEG_INF;
    }

    int chosen[4];
    #pragma unroll
    for (int p = 0; p < 4; ++p) {
        float cur = fmaxf(fmaxf(cand[0], cand[1]), fmaxf(cand[2], cand[3]));
        #pragma unroll
        for (int off = 32; off; off >>= 1)
            cur = fmaxf(cur, __shfl_xor(cur, off));
        int curb = __float_as_int(cur);
        chosen[p] = curb & 0xFFF;
        #pragma unroll
        for (int j = 0; j < 4; ++j)
            if (__float_as_int(cand[j]) == curb) cand[j] = NEG_INF;
    }

    // exact fp32 rescore of the 4 survivors (round-1-validated formula);
    // X2 via the same data layout + butterfly order as the old prep reduction.
    float4 xv = *(const float4*)(x + (size_t)row * E + lane * 4);
    float s2 = xv.x * xv.x + xv.y * xv.y + xv.z * xv.z + xv.w * xv.w;
    float d[4];
    #pragma unroll
    for (int j = 0; j < 4; ++j) {
        float4 wv = *(const float4*)(w + (size_t)chosen[j] * E + lane * 4);
        d[j] = xv.x * wv.x + xv.y * wv.y + xv.z * wv.z + xv.w * wv.w;
    }
    #pragma unroll
    for (int off = 32; off; off >>= 1) {
        s2 += __shfl_xor(s2, off);
        #pragma unroll
        for (int j = 0; j < 4; ++j) d[j] += __shfl_xor(d[j], off);
    }

    float bs = FLT_MAX; int win = INT_MAX;
    #pragma unroll
    for (int j = 0; j < 4; ++j) {
        float s = (s2 - 2.0f * d[j]) + w2[chosen[j]];
        if (lexlt(s, chosen[j], bs, win)) { bs = s; win = chosen[j]; }
    }

    if (lane == 0) qidx[row] = (float)win;
    *(float4*)(qdata + (size_t)row * E + lane * 4) =
        *(const float4*)(w + (size_t)win * E + lane * 4);
}

// ---------------------------------------------------------------------------
// Round-1 fp32 fallback (only if ws_size too small). Passed absmax 0.
// ---------------------------------------------------------------------------
constexpr int FBM = 64, FBN = 128, FBK = 64, FPAD = 4, FTH = 256;

__global__ __launch_bounds__(64) void row_sumsq_kernel(const float* __restrict__ src,
                                                       float* __restrict__ dst) {
    int row = blockIdx.x, lane = threadIdx.x;
    float4 v = ((const float4*)(src + (size_t)row * E))[lane];
    float s = v.x * v.x + v.y * v.y + v.z * v.z + v.w * v.w;
    #pragma unroll
    for (int off = 32; off > 0; off >>= 1) s += __shfl_down(s, off);
    if (lane == 0) dst[row] = s;
}

__global__ __launch_bounds__(FTH) void vq_fallback_kernel(
    const float* __restrict__ x, const float* __restrict__ w,
    const float* __restrict__ x2, const float* __restrict__ w2,
    float* __restrict__ qdata, float* __restrict__ qidx)
{
    __shared__ float xs[FBM][FBK + FPAD];
    __shared__ float ws[FBN][FBK + FPAD];
    __shared__ float redS[FBM][16];
    __shared__ int   redC[FBM][16];
    __shared__ int   bestC[FBM];

    const int tid = threadIdx.x, tr = tid >> 4, tc = tid & 15;
    const int r0 = blockIdx.x * FBM;
    float best[4]; int bidx[4];
    #pragma unroll
    for (int i = 0; i < 4; ++i) { best[i] = FLT_MAX; bidx[i] = 0x7FFFFFFF; }
    float x2r[4];
    #pragma unroll
    for (int i = 0; i < 4; ++i) x2r[i] = x2[r0 + tr + 16 * i];

    for (int qt = 0; qt < Qn / FBN; ++qt) {
        const int c0 = qt * FBN;
        float acc[4][8];
        #pragma unroll
        for (int i = 0; i < 4; ++i)
            #pragma unroll
            for (int j = 0; j < 8; ++j) acc[i][j] = 0.f;
        for (int kt = 0; kt < E / FBK; ++kt) {
            __syncthreads();
            const int kk = (tid & 15) * 4, rr = tid >> 4;
            #pragma unroll
            for (int m = 0; m < 4; ++m)
                *(float4*)&xs[m * 16 + rr][kk] =
                    *(const float4*)(x + (size_t)(r0 + m * 16 + rr) * E + kt * FBK + kk);
            #pragma unroll
            for (int m = 0; m < 8; ++m)
                *(float4*)&ws[m * 16 + rr][kk] =
                    *(const float4*)(w + (size_t)(c0 + m * 16 + rr) * E + kt * FBK + kk);
            __syncthreads();
            #pragma unroll
            for (int k4 = 0; k4 < FBK / 4; ++k4) {
                float4 a[4], bb[8];
                #pragma unroll
                for (int i = 0; i < 4; ++i) a[i] = *(const float4*)&xs[tr + 16 * i][k4 * 4];
                #pragma unroll
                for (int j = 0; j < 8; ++j) bb[j] = *(const float4*)&ws[tc + 16 * j][k4 * 4];
                #pragma unroll
                for (int i = 0; i < 4; ++i)
                    #pragma unroll
                    for (int j = 0; j < 8; ++j) {
                        acc[i][j] += a[i].x * bb[j].x; acc[i][j] += a[i].y * bb[j].y;
                        acc[i][j] += a[i].z * bb[j].z; acc[i][j] += a[i].w * bb[j].w;
                    }
            }
        }
        #pragma unroll
        for (int i = 0; i < 4; ++i)
            #pragma unroll
            for (int j = 0; j < 8; ++j) {
                int c = c0 + tc + 16 * j;
                float s = (x2r[i] - 2.0f * acc[i][j]) + w2[c];
                if (s < best[i]) { best[i] = s; bidx[i] = c; }
            }
    }
    #pragma unroll
    for (int i = 0; i < 4; ++i) { redS[tr + 16 * i][tc] = best[i]; redC[tr + 16 * i][tc] = bidx[i]; }
    __syncthreads();
    if (tid < FBM) {
        float bs = FLT_MAX; int bc = 0x7FFFFFFF;
        #pragma unroll
        for (int t = 0; t < 16; ++t) {
            float s = redS[tid][t]; int c = redC[tid][t];
            if (s < bs || (s == bs && c < bc)) { bs = s; bc = c; }
        }
        qidx[r0 + tid] = (float)bc; bestC[tid] = bc;
    }
    __syncthreads();
    for (int it = 0; it < FBM / 4; ++it) {
        int row = it * 4 + (tid >> 6), c = bestC[row], kk = (tid & 63) * 4;
        *(float4*)(qdata + (size_t)(r0 + row) * E + kk) = *(const float4*)(w + (size_t)c * E + kk);
    }
}

// ---------------------------------------------------------------------------
extern "C" void kernel_launch(void* const* d_in, const int* in_sizes, int n_in,
                              void* d_out, int out_size, void* d_ws, size_t ws_size,
                              hipStream_t stream) {
    const float* x = (const float*)d_in[0];
    const float* w = (const float*)d_in[1];
    const int N = in_sizes[0] / E;                      // 32768

    float* qdata = (float*)d_out;
    float* qidx  = (float*)d_out + (size_t)N * E;

    size_t off = 0;
    auto carve = [&](size_t bytes) { size_t p = off; off += (bytes + 255) & ~(size_t)255; return p; };
    size_t oA16 = carve((size_t)N  * 256 * sizeof(_Float16));     // 16.8 MB
    size_t oB16 = carve((size_t)Qn * 256 * sizeof(_Float16));     //  2.1 MB
    size_t ow2  = carve((size_t)Qn * sizeof(float));
    size_t oT   = carve((size_t)N * 32 * sizeof(float4));         // 16.8 MB
    size_t ox2f = carve((size_t)N * sizeof(float));               // fallback only

    if (ws_size >= off && (N % 256) == 0) {
        char* ws = (char*)d_ws;
        _Float16* A16 = (_Float16*)(ws + oA16);
        _Float16* B16 = (_Float16*)(ws + oB16);
        float* w2    = (float*)(ws + ow2);
        float4* top4 = (float4*)(ws + oT);

        prep_kernel<<<N / 4 + Qn / 4, 256, 0, stream>>>(x, w, A16, B16, w2, N / 4);
        vq_mfma_kernel<<<dim3(Qn / 256, N / 256), 512, 0, stream>>>(A16, B16, top4);
        finalize_kernel<<<N / 4, 256, 0, stream>>>(top4, x, w, w2, qdata, qidx);
    } else {
        float* x2 = (float*)d_ws;
        float* w2 = x2 + N;
        row_sumsq_kernel<<<N, 64, 0, stream>>>(x, x2);
        row_sumsq_kernel<<<Qn, 64, 0, stream>>>(w, w2);
        vq_fallback_kernel<<<N / FBM, FTH, 0, stream>>>(x, w, x2, w2, qdata, qidx);
    }
}

// Round 7
// 178.046 us; speedup vs baseline: 1.1591x; 1.1591x over previous
//
#include <hip/hip_runtime.h>
#include <cfloat>
#include <climits>

// Problem constants: x (16,2048,256) fp32 -> N=32768 rows; weight (4096,256) fp32.
constexpr int E  = 256;    // quantizing_dim
constexpr int Qn = 4096;   // num_quantizing
constexpr float WSCALE = 4096.0f;   // 2^12 exact pow2 (keeps f16 products well-scaled)

// Round 18: X-in-registers, W-streamed long loop. Six variants showed the
// invariant cost is the 4-step staged loop x 8 sequential blocks/CU. New:
// block = 128 x-rows x ALL 4096 codewords, grid = N/128 = 256 = 1 block/CU.
// X fragments (64 rows x K256 per wave = 32 half8 = 64 VGPR) are loaded ONCE
// via a coalesced LDS bounce and stay in registers. LDS = 2 x 64KB W tiles
// (128 cw x K256), double-buffered over a 32-iteration loop with the
// validated stage-early + __syncthreads schedule -- stage (64KB ~1.5k cyc)
// now fits under compute (512 MFMAs ~2.1k cyc/CU) with 32 iters to pipeline.
// Validated pieces reused verbatim: 32x32x16 MFMA layouts, fr&7 staging
// involution + read swizzle, (kt,s) accumulation order (bit-identical keys),
// packed-key top-2, exact-rescore finalize. Retention re-partitioned:
// running per-lane top-2 per 8-tile quarter (static q index) -> 16 slots/row
// -> top-4 -> finalize reads ONE float4/row (top4 buffer 16.8MB -> 512KB).

typedef _Float16 half8  __attribute__((ext_vector_type(8)));
typedef _Float16 half4v __attribute__((ext_vector_type(4)));
typedef float    f32x16 __attribute__((ext_vector_type(16)));

#define GAS __attribute__((address_space(1)))
#define LAS __attribute__((address_space(3)))

#define NEG_INF __int_as_float(0xFF800000)

__device__ inline bool lexlt(float a, int ai, float b, int bi) {
    return a < b || (a == b && ai < bi);
}

// ---------------------------------------------------------------------------
// Prep: one 64-lane wave per row (x and w). Emits f16 operand; sumsq only for w.
// (unchanged, validated)
// ---------------------------------------------------------------------------
__global__ __launch_bounds__(256) void prep_kernel(
    const float* __restrict__ x, const float* __restrict__ w,
    _Float16* __restrict__ A16, _Float16* __restrict__ B16,
    float* __restrict__ w2, int nxblocks)
{
    int blk  = blockIdx.x;
    int sub  = threadIdx.x >> 6;
    int lane = threadIdx.x & 63;
    bool isX = blk < nxblocks;
    int row  = (isX ? blk : blk - nxblocks) * 4 + sub;

    const float* src = isX ? x : w;
    float4 v = *(const float4*)(src + (size_t)row * E + lane * 4);

    if (!isX) {
        float s = v.x * v.x + v.y * v.y + v.z * v.z + v.w * v.w;   // UNSCALED sumsq
        #pragma unroll
        for (int off = 32; off; off >>= 1) s += __shfl_xor(s, off);
        if (lane == 0) w2[row] = s;
    }

    float sc = isX ? 1.0f : WSCALE;                            // exact pow2
    half4v h = { (_Float16)(v.x * sc), (_Float16)(v.y * sc),
                 (_Float16)(v.z * sc), (_Float16)(v.w * sc) };
    _Float16* dst16 = (isX ? A16 : B16) + (size_t)row * 256;
    *(half4v*)(dst16 + lane * 4) = h;
}

// ---------------------------------------------------------------------------
// Main MFMA kernel: block = 128 x-rows x all 4096 codewords (32 tiles of 128),
// 512 threads (8 waves = 4 cw-groups x 2 row-groups), grid = N/128 = 256.
// Per wave per tile: 32 cw (M=1) x 64 rows (N=2), 32 MFMAs, 16 ds_reads,
// X operand entirely in registers.
// ---------------------------------------------------------------------------
__device__ inline void ins4max(float K[4], float k) {
    #pragma unroll
    for (int t = 0; t < 4; ++t) {            // keep K descending
        float mx = fmaxf(K[t], k);
        k = fminf(K[t], k);
        K[t] = mx;
    }
}

union SmemU {
    _Float16 buf[2][4][128][64];    // [dbuf][kt][row][64 f16] = 2 x 64 KB
    float2 mergeS[128 * 16];        // 16 KB overlay: [row][cwg*4 + q]
};

__global__ __launch_bounds__(512, 2) void vq_mfma_kernel(
    const _Float16* __restrict__ A16,      // (N, 256)  xh
    const _Float16* __restrict__ B16,      // (Qn, 256) wh_s
    float4* __restrict__ top4)             // (N) packed {k0,k1,k2,k3} desc
{
    __shared__ SmemU sm;

    const int tid  = threadIdx.x;
    const int wv   = tid >> 6;           // 0..7
    const int lane = tid & 63;
    const int l31  = lane & 31;
    const int lh   = lane >> 5;          // k-half select
    const int rb   = blockIdx.x;         // x-row band (128 rows)

    const int cwg = wv & 3;              // cw group within tile: cwg*32
    const int rg  = wv >> 2;             // row group: rg*64

    const _Float16* Ab16 = A16 + (size_t)rb * 128 * 256;

    // Stage one 128-row x K256 operand block into buf[bi], layout
    // [kt][row][64], linear dest per 8-row wave slice; chunk swizzle lives in
    // the pre-swizzled GLOBAL source (rule #21 involution), read side XORs
    // the same (row&7).  8 gload_lds per thread.
    auto stage128 = [&](const _Float16* src, int bi) {
        #pragma unroll
        for (int kt = 0; kt < 4; ++kt)
            #pragma unroll
            for (int i = 0; i < 2; ++i) {
                int row  = i * 64 + wv * 8 + (lane >> 3);
                int gchk = (lane & 7) ^ (row & 7);
                const _Float16* g = src + (size_t)row * 256 + kt * 64 + gchk * 8;
                __builtin_amdgcn_global_load_lds((const GAS void*)g,
                    (LAS void*)(&sm.buf[bi][kt][i * 64 + wv * 8][0]), 16, 0, 0);
            }
    };

    // ---- prologue: bounce X through buf[0], W tile 0 into buf[1] ----
    stage128(Ab16, 0);
    stage128(B16, 1);                      // tile 0 (cw 0..127)
    __syncthreads();                       // both staged

    // X fragments -> registers (validated r12 xf addressing, rows rg*64+..)
    half8 xf[2][4][4];                     // [n][kt][s]
    #pragma unroll
    for (int n = 0; n < 2; ++n)
        #pragma unroll
        for (int kt = 0; kt < 4; ++kt)
            #pragma unroll
            for (int s = 0; s < 4; ++s) {
                int xr = rg * 64 + n * 32 + l31;
                int kc = 2 * s + lh;
                xf[n][kt][s] = *(const half8*)(&sm.buf[0][kt][0][0]
                                + xr * 64 + ((kc ^ (xr & 7)) << 3));
            }
    __syncthreads();                       // X reads done -> buf[0] free

    // running retention: per lane, top-2 per (n, 8-tile quarter)
    float t1[2][4], t2[2][4];
    #pragma unroll
    for (int n = 0; n < 2; ++n)
        #pragma unroll
        for (int q = 0; q < 4; ++q) { t1[n][q] = NEG_INF; t2[n][q] = NEG_INF; }

    const int fr = cwg * 32 + l31;         // wave's W frag row within tile
    const int frsw = fr & 7;

    // ---- 32-tile W loop: stage-early + __syncthreads (r12 schedule) ----
    #pragma unroll
    for (int q = 0; q < 4; ++q) {
        for (int tt = 0; tt < 8; ++tt) {
            const int t  = q * 8 + tt;
            const int bi = (t + 1) & 1;    // tile t lives in buf[(t+1)&1]

            if (t + 1 < 32)                // stage next tile into other buf
                stage128(B16 + (size_t)(t + 1) * 128 * 256, t & 1);

            const _Float16* Wb = &sm.buf[bi][0][0][0];

            f32x16 acc0 = {}, acc1 = {};
            __builtin_amdgcn_s_setprio(1);
            #pragma unroll
            for (int kt = 0; kt < 4; ++kt)
                #pragma unroll
                for (int s = 0; s < 4; ++s) {
                    int kc = 2 * s + lh;
                    half8 wf = *(const half8*)(Wb + kt * 8192
                                  + fr * 64 + ((kc ^ frsw) << 3));
                    acc0 = __builtin_amdgcn_mfma_f32_32x32x16_f16(
                               wf, xf[0][kt][s], acc0, 0, 0, 0);
                    acc1 = __builtin_amdgcn_mfma_f32_32x32x16_f16(
                               wf, xf[1][kt][s], acc1, 0, 0, 0);
                }
            __builtin_amdgcn_s_setprio(0);

            // retire tile t: packed key = (bits & ~0xFFF) | cw ; top-2 update
            #pragma unroll
            for (int r = 0; r < 16; ++r) {
                int crow = (r & 3) + 8 * (r >> 2) + 4 * lh;   // C-row (32x32)
                int qg   = t * 128 + cwg * 32 + crow;         // global cw id
                float pk0 = __int_as_float(
                    (__float_as_int(acc0[r]) & 0xFFFFF000) | qg);
                t2[0][q] = __builtin_amdgcn_fmed3f(t1[0][q], t2[0][q], pk0);
                t1[0][q] = fmaxf(t1[0][q], pk0);
                float pk1 = __int_as_float(
                    (__float_as_int(acc1[r]) & 0xFFFFF000) | qg);
                t2[1][q] = __builtin_amdgcn_fmed3f(t1[1][q], t2[1][q], pk1);
                t1[1][q] = fmaxf(t1[1][q], pk1);
            }

            __syncthreads();               // stage(t+1) landed; buf swap safe
        }
    }

    // ---- merge: lh-pair shuffle, then 16 slots/row in LDS, then top-4 ----
    #pragma unroll
    for (int n = 0; n < 2; ++n)
        #pragma unroll
        for (int q = 0; q < 4; ++q) {
            float o1 = __shfl_xor(t1[n][q], 32);
            float o2 = __shfl_xor(t2[n][q], 32);
            float m1 = fmaxf(t1[n][q], o1);
            float m2 = __builtin_amdgcn_fmed3f(t1[n][q], o1,
                                               fmaxf(t2[n][q], o2));
            t1[n][q] = m1; t2[n][q] = m2;  // merged top-2 of the lane pair
        }

    // (last tile read buf[0]; overlay written only after the loop's final sync)
    if (lh == 0) {
        #pragma unroll
        for (int n = 0; n < 2; ++n) {
            int row = rg * 64 + n * 32 + l31;
            #pragma unroll
            for (int q = 0; q < 4; ++q)
                sm.mergeS[row * 16 + cwg * 4 + q] =
                    make_float2(t1[n][q], t2[n][q]);
        }
    }
    __syncthreads();

    if (tid < 128) {
        float K[4] = { NEG_INF, NEG_INF, NEG_INF, NEG_INF };
        #pragma unroll
        for (int sl = 0; sl < 16; ++sl) {
            float2 a = sm.mergeS[tid * 16 + sl];
            ins4max(K, a.x);
            ins4max(K, a.y);
        }
        top4[(size_t)rb * 128 + tid] = make_float4(K[0], K[1], K[2], K[3]);
    }
}

// ---------------------------------------------------------------------------
// Finalize: per row, 4 packed candidates (already global top-4 by key) ->
// exact fp32 rescore (reference formula + first-index tie-break), write
// outputs. Rescore math verbatim from the validated kernel.
// ---------------------------------------------------------------------------
__global__ __launch_bounds__(256) void finalize_kernel(
    const float4* __restrict__ top4, const float* __restrict__ x,
    const float* __restrict__ w, const float* __restrict__ w2,
    float* __restrict__ qdata, float* __restrict__ qidx)
{
    int row  = blockIdx.x * 4 + (threadIdx.x >> 6);
    int lane = threadIdx.x & 63;

    float4 c4 = top4[row];
    int chosen[4] = { __float_as_int(c4.x) & 0xFFF,
                      __float_as_int(c4.y) & 0xFFF,
                      __float_as_int(c4.z) & 0xFFF,
                      __float_as_int(c4.w) & 0xFFF };

    // exact fp32 rescore of the 4 survivors (round-1-validated formula);
    // X2 via the same data layout + butterfly order as the validated prep.
    float4 xv = *(const float4*)(x + (size_t)row * E + lane * 4);
    float s2 = xv.x * xv.x + xv.y * xv.y + xv.z * xv.z + xv.w * xv.w;
    float d[4];
    #pragma unroll
    for (int j = 0; j < 4; ++j) {
        float4 wv = *(const float4*)(w + (size_t)chosen[j] * E + lane * 4);
        d[j] = xv.x * wv.x + xv.y * wv.y + xv.z * wv.z + xv.w * wv.w;
    }
    #pragma unroll
    for (int off = 32; off; off >>= 1) {
        s2 += __shfl_xor(s2, off);
        #pragma unroll
        for (int j = 0; j < 4; ++j) d[j] += __shfl_xor(d[j], off);
    }

    float bs = FLT_MAX; int win = INT_MAX;
    #pragma unroll
    for (int j = 0; j < 4; ++j) {
        float s = (s2 - 2.0f * d[j]) + w2[chosen[j]];
        if (lexlt(s, chosen[j], bs, win)) { bs = s; win = chosen[j]; }
    }

    if (lane == 0) qidx[row] = (float)win;
    *(float4*)(qdata + (size_t)row * E + lane * 4) =
        *(const float4*)(w + (size_t)win * E + lane * 4);
}

// ---------------------------------------------------------------------------
// Round-1 fp32 fallback (only if ws_size too small). Passed absmax 0.
// ---------------------------------------------------------------------------
constexpr int FBM = 64, FBN = 128, FBK = 64, FPAD = 4, FTH = 256;

__global__ __launch_bounds__(64) void row_sumsq_kernel(const float* __restrict__ src,
                                                       float* __restrict__ dst) {
    int row = blockIdx.x, lane = threadIdx.x;
    float4 v = ((const float4*)(src + (size_t)row * E))[lane];
    float s = v.x * v.x + v.y * v.y + v.z * v.z + v.w * v.w;
    #pragma unroll
    for (int off = 32; off > 0; off >>= 1) s += __shfl_down(s, off);
    if (lane == 0) dst[row] = s;
}

__global__ __launch_bounds__(FTH) void vq_fallback_kernel(
    const float* __restrict__ x, const float* __restrict__ w,
    const float* __restrict__ x2, const float* __restrict__ w2,
    float* __restrict__ qdata, float* __restrict__ qidx)
{
    __shared__ float xs[FBM][FBK + FPAD];
    __shared__ float ws[FBN][FBK + FPAD];
    __shared__ float redS[FBM][16];
    __shared__ int   redC[FBM][16];
    __shared__ int   bestC[FBM];

    const int tid = threadIdx.x, tr = tid >> 4, tc = tid & 15;
    const int r0 = blockIdx.x * FBM;
    float best[4]; int bidx[4];
    #pragma unroll
    for (int i = 0; i < 4; ++i) { best[i] = FLT_MAX; bidx[i] = 0x7FFFFFFF; }
    float x2r[4];
    #pragma unroll
    for (int i = 0; i < 4; ++i) x2r[i] = x2[r0 + tr + 16 * i];

    for (int qt = 0; qt < Qn / FBN; ++qt) {
        const int c0 = qt * FBN;
        float acc[4][8];
        #pragma unroll
        for (int i = 0; i < 4; ++i)
            #pragma unroll
            for (int j = 0; j < 8; ++j) acc[i][j] = 0.f;
        for (int kt = 0; kt < E / FBK; ++kt) {
            __syncthreads();
            const int kk = (tid & 15) * 4, rr = tid >> 4;
            #pragma unroll
            for (int m = 0; m < 4; ++m)
                *(float4*)&xs[m * 16 + rr][kk] =
                    *(const float4*)(x + (size_t)(r0 + m * 16 + rr) * E + kt * FBK + kk);
            #pragma unroll
            for (int m = 0; m < 8; ++m)
                *(float4*)&ws[m * 16 + rr][kk] =
                    *(const float4*)(w + (size_t)(c0 + m * 16 + rr) * E + kt * FBK + kk);
            __syncthreads();
            #pragma unroll
            for (int k4 = 0; k4 < FBK / 4; ++k4) {
                float4 a[4], bb[8];
                #pragma unroll
                for (int i = 0; i < 4; ++i) a[i] = *(const float4*)&xs[tr + 16 * i][k4 * 4];
                #pragma unroll
                for (int j = 0; j < 8; ++j) bb[j] = *(const float4*)&ws[tc + 16 * j][k4 * 4];
                #pragma unroll
                for (int i = 0; i < 4; ++i)
                    #pragma unroll
                    for (int j = 0; j < 8; ++j) {
                        acc[i][j] += a[i].x * bb[j].x; acc[i][j] += a[i].y * bb[j].y;
                        acc[i][j] += a[i].z * bb[j].z; acc[i][j] += a[i].w * bb[j].w;
                    }
            }
        }
        #pragma unroll
        for (int i = 0; i < 4; ++i)
            #pragma unroll
            for (int j = 0; j < 8; ++j) {
                int c = c0 + tc + 16 * j;
                float s = (x2r[i] - 2.0f * acc[i][j]) + w2[c];
                if (s < best[i]) { best[i] = s; bidx[i] = c; }
            }
    }
    #pragma unroll
    for (int i = 0; i < 4; ++i) { redS[tr + 16 * i][tc] = best[i]; redC[tr + 16 * i][tc] = bidx[i]; }
    __syncthreads();
    if (tid < FBM) {
        float bs = FLT_MAX; int bc = 0x7FFFFFFF;
        #pragma unroll
        for (int t = 0; t < 16; ++t) {
            float s = redS[tid][t]; int c = redC[tid][t];
            if (s < bs || (s == bs && c < bc)) { bs = s; bc = c; }
        }
        qidx[r0 + tid] = (float)bc; bestC[tid] = bc;
    }
    __syncthreads();
    for (int it = 0; it < FBM / 4; ++it) {
        int row = it * 4 + (tid >> 6), c = bestC[row], kk = (tid & 63) * 4;
        *(float4*)(qdata + (size_t)(r0 + row) * E + kk) = *(const float4*)(w + (size_t)c * E + kk);
    }
}

// ---------------------------------------------------------------------------
extern "C" void kernel_launch(void* const* d_in, const int* in_sizes, int n_in,
                              void* d_out, int out_size, void* d_ws, size_t ws_size,
                              hipStream_t stream) {
    const float* x = (const float*)d_in[0];
    const float* w = (const float*)d_in[1];
    const int N = in_sizes[0] / E;                      // 32768

    float* qdata = (float*)d_out;
    float* qidx  = (float*)d_out + (size_t)N * E;

    size_t off = 0;
    auto carve = [&](size_t bytes) { size_t p = off; off += (bytes + 255) & ~(size_t)255; return p; };
    size_t oA16 = carve((size_t)N  * 256 * sizeof(_Float16));     // 16.8 MB
    size_t oB16 = carve((size_t)Qn * 256 * sizeof(_Float16));     //  2.1 MB
    size_t ow2  = carve((size_t)Qn * sizeof(float));
    size_t oT   = carve((size_t)N * sizeof(float4));              // 512 KB
    size_t ox2f = carve((size_t)N * sizeof(float));               // fallback only

    if (ws_size >= off && (N % 128) == 0) {
        char* ws = (char*)d_ws;
        _Float16* A16 = (_Float16*)(ws + oA16);
        _Float16* B16 = (_Float16*)(ws + oB16);
        float* w2    = (float*)(ws + ow2);
        float4* top4 = (float4*)(ws + oT);

        prep_kernel<<<N / 4 + Qn / 4, 256, 0, stream>>>(x, w, A16, B16, w2, N / 4);
        vq_mfma_kernel<<<N / 128, 512, 0, stream>>>(A16, B16, top4);
        finalize_kernel<<<N / 4, 256, 0, stream>>>(top4, x, w, w2, qdata, qidx);
    } else {
        float* x2 = (float*)d_ws;
        float* w2 = x2 + N;
        row_sumsq_kernel<<<N, 64, 0, stream>>>(x, x2);
        row_sumsq_kernel<<<Qn, 64, 0, stream>>>(w, w2);
        vq_fallback_kernel<<<N / FBM, FTH, 0, stream>>>(x, w, x2, w2, qdata, qidx);
    }
}

// Round 8
// 176.593 us; speedup vs baseline: 1.1686x; 1.0082x over previous
//
#include <hip/hip_runtime.h>
#include <cfloat>
#include <climits>

// Problem constants: x (16,2048,256) fp32 -> N=32768 rows; weight (4096,256) fp32.
constexpr int E  = 256;    // quantizing_dim
constexpr int Qn = 4096;   // num_quantizing
constexpr float WSCALE = 4096.0f;   // 2^12 exact pow2 (keeps f16 products well-scaled)

// Round 19: r18 (83us, X-in-regs + W-streamed 32-iter loop) + genuine 3-deep
// prefetch. r18's residual stall: the end-of-iter __syncthreads drains the
// stage issued in the SAME iteration (tail latency exposed 32x, 2 waves/SIMD
// lockstep). Fix: half-K W tiles (128cw x K128 = 32KB) -> 4 LDS slots, 64
// iters, stage(t+3) issued in iter t, top-of-iter s_waitcnt vmcnt(8) waits a
// stage issued THREE iterations (~9k cyc) ago; ONE no-drain barrier/iter
// (WAR: stage(t+3) overwrites the slot read in iter t-1, fenced by the same
// barrier; RAW: own vmcnt + barrier => all waves' stage(t) landed). Peeled
// t=62 (vmcnt 4), t=63 (vmcnt 0). Numerics bit-identical to r18: k-halves of
// each cw-tile processed consecutively in the same (kt,s) order into the same
// acc; retention retires at h=1 with identical qg and quarter q=ct>>3; h is a
// compile-time macro literal (rule #20); "memory"-clobber asm fences order
// LDS/VMEM ops around the raw barrier (rule #18).

typedef _Float16 half8  __attribute__((ext_vector_type(8)));
typedef _Float16 half4v __attribute__((ext_vector_type(4)));
typedef float    f32x16 __attribute__((ext_vector_type(16)));

#define GAS __attribute__((address_space(1)))
#define LAS __attribute__((address_space(3)))

#define NEG_INF __int_as_float(0xFF800000)

__device__ inline bool lexlt(float a, int ai, float b, int bi) {
    return a < b || (a == b && ai < bi);
}

// ---------------------------------------------------------------------------
// Prep: one 64-lane wave per row (x and w). Emits f16 operand; sumsq only for w.
// (unchanged, validated)
// ---------------------------------------------------------------------------
__global__ __launch_bounds__(256) void prep_kernel(
    const float* __restrict__ x, const float* __restrict__ w,
    _Float16* __restrict__ A16, _Float16* __restrict__ B16,
    float* __restrict__ w2, int nxblocks)
{
    int blk  = blockIdx.x;
    int sub  = threadIdx.x >> 6;
    int lane = threadIdx.x & 63;
    bool isX = blk < nxblocks;
    int row  = (isX ? blk : blk - nxblocks) * 4 + sub;

    const float* src = isX ? x : w;
    float4 v = *(const float4*)(src + (size_t)row * E + lane * 4);

    if (!isX) {
        float s = v.x * v.x + v.y * v.y + v.z * v.z + v.w * v.w;   // UNSCALED sumsq
        #pragma unroll
        for (int off = 32; off; off >>= 1) s += __shfl_xor(s, off);
        if (lane == 0) w2[row] = s;
    }

    float sc = isX ? 1.0f : WSCALE;                            // exact pow2
    half4v h = { (_Float16)(v.x * sc), (_Float16)(v.y * sc),
                 (_Float16)(v.z * sc), (_Float16)(v.w * sc) };
    _Float16* dst16 = (isX ? A16 : B16) + (size_t)row * 256;
    *(half4v*)(dst16 + lane * 4) = h;
}

// ---------------------------------------------------------------------------
// Main MFMA kernel: block = 128 x-rows x all 4096 codewords, 512 threads
// (8 waves = 4 cwg x 2 rg), grid = N/128 = 256 (1 block/CU). X in registers;
// W streamed as 64 half-K tiles (128cw x K128 = 32KB) through 4 LDS slots
// with 3-deep prefetch and counted vmcnt.
// ---------------------------------------------------------------------------
__device__ inline void ins4max(float K[4], float k) {
    #pragma unroll
    for (int t = 0; t < 4; ++t) {            // keep K descending
        float mx = fmaxf(K[t], k);
        k = fminf(K[t], k);
        K[t] = mx;
    }
}

union SmemU {
    _Float16 buf[4][2][128][64];    // [slot][ktl][row][64 f16] = 4 x 32 KB
    float2 mergeS[128 * 16];        // 16 KB overlay: [row][cwg*4 + q]
};

// one K-half-tile step; H is a literal 0/1 (rule #20: xf indices static)
#define KSTEP(T, VMSTR, Q, H)                                              \
  {                                                                        \
    asm volatile("s_waitcnt " VMSTR ::: "memory");                         \
    __builtin_amdgcn_s_barrier();                                          \
    asm volatile("" ::: "memory");                                         \
    const int t_ = (T);                                                    \
    if (t_ + 3 < 64) stage_t(t_ + 3);                                      \
    const _Float16* Wb = &sm.buf[t_ & 3][0][0][0];                         \
    if ((H) == 0) { acc0 = (f32x16){}; acc1 = (f32x16){}; }                \
    __builtin_amdgcn_s_setprio(1);                                         \
    _Pragma("unroll")                                                      \
    for (int ktl = 0; ktl < 2; ++ktl)                                      \
      _Pragma("unroll")                                                    \
      for (int s = 0; s < 4; ++s) {                                        \
        int kc = 2 * s + lh;                                               \
        half8 wf = *(const half8*)(Wb + ktl * 8192                         \
                      + fr * 64 + ((kc ^ frsw) << 3));                     \
        acc0 = __builtin_amdgcn_mfma_f32_32x32x16_f16(                     \
                   wf, xf[0][2 * (H) + ktl][s], acc0, 0, 0, 0);            \
        acc1 = __builtin_amdgcn_mfma_f32_32x32x16_f16(                     \
                   wf, xf[1][2 * (H) + ktl][s], acc1, 0, 0, 0);            \
      }                                                                    \
    __builtin_amdgcn_s_setprio(0);                                         \
    if ((H) == 1) {                                                        \
      const int ct_ = t_ >> 1;                                             \
      _Pragma("unroll")                                                    \
      for (int r = 0; r < 16; ++r) {                                       \
        int crow = (r & 3) + 8 * (r >> 2) + 4 * lh;                        \
        int qg   = ct_ * 128 + cwg * 32 + crow;                            \
        float pk0 = __int_as_float(                                        \
            (__float_as_int(acc0[r]) & 0xFFFFF000) | qg);                  \
        t2[0][(Q)] = __builtin_amdgcn_fmed3f(t1[0][(Q)], t2[0][(Q)], pk0); \
        t1[0][(Q)] = fmaxf(t1[0][(Q)], pk0);                               \
        float pk1 = __int_as_float(                                        \
            (__float_as_int(acc1[r]) & 0xFFFFF000) | qg);                  \
        t2[1][(Q)] = __builtin_amdgcn_fmed3f(t1[1][(Q)], t2[1][(Q)], pk1); \
        t1[1][(Q)] = fmaxf(t1[1][(Q)], pk1);                               \
      }                                                                    \
    }                                                                      \
  }

__global__ __launch_bounds__(512, 2) void vq_mfma_kernel(
    const _Float16* __restrict__ A16,      // (N, 256)  xh
    const _Float16* __restrict__ B16,      // (Qn, 256) wh_s
    float4* __restrict__ top4)             // (N) packed {k0,k1,k2,k3} desc
{
    __shared__ SmemU sm;

    const int tid  = threadIdx.x;
    const int wv   = tid >> 6;           // 0..7
    const int lane = tid & 63;
    const int l31  = lane & 31;
    const int lh   = lane >> 5;          // k-half select
    const int rb   = blockIdx.x;         // x-row band (128 rows)

    const int cwg = wv & 3;              // cw group within tile: cwg*32
    const int rg  = wv >> 2;             // row group: rg*64

    const int srow = lane >> 3;
    const int schk = lane & 7;

    const _Float16* Ab16 = A16 + (size_t)rb * 128 * 256;

    // Stage K-half h of a 128-row operand block into slot. Linear dest per
    // 8-row group (gload_lds constraint); chunk swizzle in the pre-swizzled
    // GLOBAL source (rule #21 involution). 4 gload_lds per thread.
    auto stage_half = [&](const _Float16* src, int slot, int h) {
        #pragma unroll
        for (int ktl = 0; ktl < 2; ++ktl)
            #pragma unroll
            for (int i = 0; i < 2; ++i) {
                int row  = i * 64 + wv * 8 + srow;
                int gchk = schk ^ (row & 7);
                const _Float16* g = src + (size_t)row * 256
                                    + (2 * h + ktl) * 64 + gchk * 8;
                __builtin_amdgcn_global_load_lds((const GAS void*)g,
                    (LAS void*)(&sm.buf[slot][ktl][i * 64 + wv * 8][0]),
                    16, 0, 0);
            }
    };
    // W half-tile t: ct = t>>1 (cw block), h = t&1 (k-half), slot = t&3
    auto stage_t = [&](int t) {
        stage_half(B16 + (size_t)(t >> 1) * 128 * 256, t & 3, t & 1);
    };

    // ---- prologue: bounce X through slots 0/1, load xf registers ----
    stage_half(Ab16, 0, 0);                // slot0 = X kt{0,1}
    stage_half(Ab16, 1, 1);                // slot1 = X kt{2,3}
    __syncthreads();

    half8 xf[2][4][4];                     // [n][kt][s]
    #pragma unroll
    for (int n = 0; n < 2; ++n)
        #pragma unroll
        for (int kt = 0; kt < 4; ++kt)
            #pragma unroll
            for (int s = 0; s < 4; ++s) {
                int xr = rg * 64 + n * 32 + l31;
                int kc = 2 * s + lh;
                xf[n][kt][s] = *(const half8*)(&sm.buf[kt >> 1][kt & 1][0][0]
                                + xr * 64 + ((kc ^ (xr & 7)) << 3));
            }
    __syncthreads();                       // xf in regs -> slots 0/1 free

    // ---- prologue: 3 half-tiles in flight ----
    stage_t(0); stage_t(1); stage_t(2);    // 12 loads/thread outstanding

    // running retention: per lane, top-2 per (n, quarter of cw-tiles)
    float t1[2][4], t2[2][4];
    #pragma unroll
    for (int n = 0; n < 2; ++n)
        #pragma unroll
        for (int q = 0; q < 4; ++q) { t1[n][q] = NEG_INF; t2[n][q] = NEG_INF; }

    const int fr   = cwg * 32 + l31;       // wave's W frag row within tile
    const int frsw = fr & 7;

    f32x16 acc0, acc1;

    // ---- 64-step loop (32 cw-tiles x 2 k-halves), pairs keep H literal ----
    #pragma unroll
    for (int q = 0; q < 4; ++q) {
        const int nct = (q == 3) ? 7 : 8;
        for (int ctt = 0; ctt < nct; ++ctt) {
            const int t0 = (q * 8 + ctt) * 2;
            KSTEP(t0,     "vmcnt(8)", q, 0);
            KSTEP(t0 + 1, "vmcnt(8)", q, 1);
        }
    }
    KSTEP(62, "vmcnt(4)", 3, 0);
    KSTEP(63, "vmcnt(0)", 3, 1);

    // ---- merge: lh-pair shuffle, then 16 slots/row in LDS, then top-4 ----
    #pragma unroll
    for (int n = 0; n < 2; ++n)
        #pragma unroll
        for (int q = 0; q < 4; ++q) {
            float o1 = __shfl_xor(t1[n][q], 32);
            float o2 = __shfl_xor(t2[n][q], 32);
            float m1 = fmaxf(t1[n][q], o1);
            float m2 = __builtin_amdgcn_fmed3f(t1[n][q], o1,
                                               fmaxf(t2[n][q], o2));
            t1[n][q] = m1; t2[n][q] = m2;  // merged top-2 of the lane pair
        }

    __syncthreads();                       // all tile reads done -> overlay

    if (lh == 0) {
        #pragma unroll
        for (int n = 0; n < 2; ++n) {
            int row = rg * 64 + n * 32 + l31;
            #pragma unroll
            for (int q = 0; q < 4; ++q)
                sm.mergeS[row * 16 + cwg * 4 + q] =
                    make_float2(t1[n][q], t2[n][q]);
        }
    }
    __syncthreads();

    if (tid < 128) {
        float K[4] = { NEG_INF, NEG_INF, NEG_INF, NEG_INF };
        #pragma unroll
        for (int sl = 0; sl < 16; ++sl) {
            float2 a = sm.mergeS[tid * 16 + sl];
            ins4max(K, a.x);
            ins4max(K, a.y);
        }
        top4[(size_t)rb * 128 + tid] = make_float4(K[0], K[1], K[2], K[3]);
    }
}

// ---------------------------------------------------------------------------
// Finalize: per row, 4 packed candidates (already global top-4 by key) ->
// exact fp32 rescore (reference formula + first-index tie-break), write
// outputs. (unchanged, validated)
// ---------------------------------------------------------------------------
__global__ __launch_bounds__(256) void finalize_kernel(
    const float4* __restrict__ top4, const float* __restrict__ x,
    const float* __restrict__ w, const float* __restrict__ w2,
    float* __restrict__ qdata, float* __restrict__ qidx)
{
    int row  = blockIdx.x * 4 + (threadIdx.x >> 6);
    int lane = threadIdx.x & 63;

    float4 c4 = top4[row];
    int chosen[4] = { __float_as_int(c4.x) & 0xFFF,
                      __float_as_int(c4.y) & 0xFFF,
                      __float_as_int(c4.z) & 0xFFF,
                      __float_as_int(c4.w) & 0xFFF };

    // exact fp32 rescore of the 4 survivors (round-1-validated formula);
    // X2 via the same data layout + butterfly order as the validated prep.
    float4 xv = *(const float4*)(x + (size_t)row * E + lane * 4);
    float s2 = xv.x * xv.x + xv.y * xv.y + xv.z * xv.z + xv.w * xv.w;
    float d[4];
    #pragma unroll
    for (int j = 0; j < 4; ++j) {
        float4 wv = *(const float4*)(w + (size_t)chosen[j] * E + lane * 4);
        d[j] = xv.x * wv.x + xv.y * wv.y + xv.z * wv.z + xv.w * wv.w;
    }
    #pragma unroll
    for (int off = 32; off; off >>= 1) {
        s2 += __shfl_xor(s2, off);
        #pragma unroll
        for (int j = 0; j < 4; ++j) d[j] += __shfl_xor(d[j], off);
    }

    float bs = FLT_MAX; int win = INT_MAX;
    #pragma unroll
    for (int j = 0; j < 4; ++j) {
        float s = (s2 - 2.0f * d[j]) + w2[chosen[j]];
        if (lexlt(s, chosen[j], bs, win)) { bs = s; win = chosen[j]; }
    }

    if (lane == 0) qidx[row] = (float)win;
    *(float4*)(qdata + (size_t)row * E + lane * 4) =
        *(const float4*)(w + (size_t)win * E + lane * 4);
}

// ---------------------------------------------------------------------------
// Round-1 fp32 fallback (only if ws_size too small). Passed absmax 0.
// ---------------------------------------------------------------------------
constexpr int FBM = 64, FBN = 128, FBK = 64, FPAD = 4, FTH = 256;

__global__ __launch_bounds__(64) void row_sumsq_kernel(const float* __restrict__ src,
                                                       float* __restrict__ dst) {
    int row = blockIdx.x, lane = threadIdx.x;
    float4 v = ((const float4*)(src + (size_t)row * E))[lane];
    float s = v.x * v.x + v.y * v.y + v.z * v.z + v.w * v.w;
    #pragma unroll
    for (int off = 32; off > 0; off >>= 1) s += __shfl_down(s, off);
    if (lane == 0) dst[row] = s;
}

__global__ __launch_bounds__(FTH) void vq_fallback_kernel(
    const float* __restrict__ x, const float* __restrict__ w,
    const float* __restrict__ x2, const float* __restrict__ w2,
    float* __restrict__ qdata, float* __restrict__ qidx)
{
    __shared__ float xs[FBM][FBK + FPAD];
    __shared__ float ws[FBN][FBK + FPAD];
    __shared__ float redS[FBM][16];
    __shared__ int   redC[FBM][16];
    __shared__ int   bestC[FBM];

    const int tid = threadIdx.x, tr = tid >> 4, tc = tid & 15;
    const int r0 = blockIdx.x * FBM;
    float best[4]; int bidx[4];
    #pragma unroll
    for (int i = 0; i < 4; ++i) { best[i] = FLT_MAX; bidx[i] = 0x7FFFFFFF; }
    float x2r[4];
    #pragma unroll
    for (int i = 0; i < 4; ++i) x2r[i] = x2[r0 + tr + 16 * i];

    for (int qt = 0; qt < Qn / FBN; ++qt) {
        const int c0 = qt * FBN;
        float acc[4][8];
        #pragma unroll
        for (int i = 0; i < 4; ++i)
            #pragma unroll
            for (int j = 0; j < 8; ++j) acc[i][j] = 0.f;
        for (int kt = 0; kt < E / FBK; ++kt) {
            __syncthreads();
            const int kk = (tid & 15) * 4, rr = tid >> 4;
            #pragma unroll
            for (int m = 0; m < 4; ++m)
                *(float4*)&xs[m * 16 + rr][kk] =
                    *(const float4*)(x + (size_t)(r0 + m * 16 + rr) * E + kt * FBK + kk);
            #pragma unroll
            for (int m = 0; m < 8; ++m)
                *(float4*)&ws[m * 16 + rr][kk] =
                    *(const float4*)(w + (size_t)(c0 + m * 16 + rr) * E + kt * FBK + kk);
            __syncthreads();
            #pragma unroll
            for (int k4 = 0; k4 < FBK / 4; ++k4) {
                float4 a[4], bb[8];
                #pragma unroll
                for (int i = 0; i < 4; ++i) a[i] = *(const float4*)&xs[tr + 16 * i][k4 * 4];
                #pragma unroll
                for (int j = 0; j < 8; ++j) bb[j] = *(const float4*)&ws[tc + 16 * j][k4 * 4];
                #pragma unroll
                for (int i = 0; i < 4; ++i)
                    #pragma unroll
                    for (int j = 0; j < 8; ++j) {
                        acc[i][j] += a[i].x * bb[j].x; acc[i][j] += a[i].y * bb[j].y;
                        acc[i][j] += a[i].z * bb[j].z; acc[i][j] += a[i].w * bb[j].w;
                    }
            }
        }
        #pragma unroll
        for (int i = 0; i < 4; ++i)
            #pragma unroll
            for (int j = 0; j < 8; ++j) {
                int c = c0 + tc + 16 * j;
                float s = (x2r[i] - 2.0f * acc[i][j]) + w2[c];
                if (s < best[i]) { best[i] = s; bidx[i] = c; }
            }
    }
    #pragma unroll
    for (int i = 0; i < 4; ++i) { redS[tr + 16 * i][tc] = best[i]; redC[tr + 16 * i][tc] = bidx[i]; }
    __syncthreads();
    if (tid < FBM) {
        float bs = FLT_MAX; int bc = 0x7FFFFFFF;
        #pragma unroll
        for (int t = 0; t < 16; ++t) {
            float s = redS[tid][t]; int c = redC[tid][t];
            if (s < bs || (s == bs && c < bc)) { bs = s; bc = c; }
        }
        qidx[r0 + tid] = (float)bc; bestC[tid] = bc;
    }
    __syncthreads();
    for (int it = 0; it < FBM / 4; ++it) {
        int row = it * 4 + (tid >> 6), c = bestC[row], kk = (tid & 63) * 4;
        *(float4*)(qdata + (size_t)(r0 + row) * E + kk) = *(const float4*)(w + (size_t)c * E + kk);
    }
}

// ---------------------------------------------------------------------------
extern "C" void kernel_launch(void* const* d_in, const int* in_sizes, int n_in,
                              void* d_out, int out_size, void* d_ws, size_t ws_size,
                              hipStream_t stream) {
    const float* x = (const float*)d_in[0];
    const float* w = (const float*)d_in[1];
    const int N = in_sizes[0] / E;                      // 32768

    float* qdata = (float*)d_out;
    float* qidx  = (float*)d_out + (size_t)N * E;

    size_t off = 0;
    auto carve = [&](size_t bytes) { size_t p = off; off += (bytes + 255) & ~(size_t)255; return p; };
    size_t oA16 = carve((size_t)N  * 256 * sizeof(_Float16));     // 16.8 MB
    size_t oB16 = carve((size_t)Qn * 256 * sizeof(_Float16));     //  2.1 MB
    size_t ow2  = carve((size_t)Qn * sizeof(float));
    size_t oT   = carve((size_t)N * sizeof(float4));              // 512 KB
    size_t ox2f = carve((size_t)N * sizeof(float));               // fallback only

    if (ws_size >= off && (N % 128) == 0) {
        char* ws = (char*)d_ws;
        _Float16* A16 = (_Float16*)(ws + oA16);
        _Float16* B16 = (_Float16*)(ws + oB16);
        float* w2    = (float*)(ws + ow2);
        float4* top4 = (float4*)(ws + oT);

        prep_kernel<<<N / 4 + Qn / 4, 256, 0, stream>>>(x, w, A16, B16, w2, N / 4);
        vq_mfma_kernel<<<N / 128, 512, 0, stream>>>(A16, B16, top4);
        finalize_kernel<<<N / 4, 256, 0, stream>>>(top4, x, w, w2, qdata, qidx);
    } else {
        float* x2 = (float*)d_ws;
        float* w2 = x2 + N;
        row_sumsq_kernel<<<N, 64, 0, stream>>>(x, x2);
        row_sumsq_kernel<<<Qn, 64, 0, stream>>>(w, w2);
        vq_fallback_kernel<<<N / FBM, FTH, 0, stream>>>(x, w, x2, w2, qdata, qidx);
    }
}